// Round 10
// baseline (128.444 us; speedup 1.0000x reference)
//
#include <hip/hip_runtime.h>

typedef __attribute__((ext_vector_type(8))) short bf16x8;
typedef __attribute__((ext_vector_type(4))) float f32x4;
typedef unsigned short ushort_t;

#define NB 32
#define NA 1024
#define NATOMS (NB*NA)
#define D  384
#define H1 256
#define H2 192
#define NE 4
#define TA 64
#define NGRID 515            // max sum of ceil(n_e/64)

__device__ __forceinline__ ushort_t f2bf(float f) {
    union { float f; unsigned u; } v; v.f = f;
    unsigned r = v.u + 0x7FFF + ((v.u >> 16) & 1);   // RNE
    return (ushort_t)(r >> 16);
}

// volatile asm load: cannot be collapsed/sunk by the scheduler; no implicit wait
__device__ __forceinline__ uint4 gload16(const ushort_t* p) {
    uint4 r;
    asm volatile("global_load_dwordx4 %0, %1, off" : "=v"(r) : "v"(p));
    return r;
}
#define WAITV6 do{ asm volatile("s_waitcnt vmcnt(6)"); __builtin_amdgcn_sched_barrier(0);}while(0)
#define WAITV4 do{ asm volatile("s_waitcnt vmcnt(4)"); __builtin_amdgcn_sched_barrier(0);}while(0)
#define WAITV2 do{ asm volatile("s_waitcnt vmcnt(2)"); __builtin_amdgcn_sched_barrier(0);}while(0)
#define WAITV0 do{ asm volatile("s_waitcnt vmcnt(0)"); __builtin_amdgcn_sched_barrier(0);}while(0)

// per-wave ballot histogram -> 4 atomics per block -> rank write
__global__ __launch_bounds__(256) void scatter_kernel(
    const int* __restrict__ species, int* __restrict__ counts, int* __restrict__ bucket)
{
    __shared__ int wcnt[4][4];
    __shared__ int wbase[4][4];
    const int t = threadIdx.x, lane = t & 63, wv = t >> 6;
    const int i = blockIdx.x * 256 + t;
    const int e = species[i];

    unsigned long long m0 = __ballot(e == 0);
    unsigned long long m1 = __ballot(e == 1);
    unsigned long long m2 = __ballot(e == 2);
    unsigned long long m3 = __ballot(e == 3);
    unsigned long long mym = (e == 0) ? m0 : (e == 1) ? m1 : (e == 2) ? m2 : m3;
    const unsigned long long lt = (lane == 63) ? 0x7FFFFFFFFFFFFFFFull
                                               : ((1ull << lane) - 1ull);
    const int rank = __popcll(mym & lt);

    if (lane == 0) {
        wcnt[wv][0] = __popcll(m0); wcnt[wv][1] = __popcll(m1);
        wcnt[wv][2] = __popcll(m2); wcnt[wv][3] = __popcll(m3);
    }
    __syncthreads();
    if (t < NE) {
        int s = t;
        int tot = wcnt[0][s] + wcnt[1][s] + wcnt[2][s] + wcnt[3][s];
        int b = atomicAdd(&counts[s], tot);
        for (int w = 0; w < 4; ++w) { wbase[w][s] = b; b += wcnt[w][s]; }
    }
    __syncthreads();
    bucket[(e << 15) + wbase[wv][e] + rank] = i;
}

// fused transpose+convert (W1 and Wh) + counts zeroing (runs BEFORE scatter)
__global__ __launch_bounds__(256) void transpose_kernel(
    const float* __restrict__ W1, const float* __restrict__ Wh,
    ushort_t* __restrict__ w1t, ushort_t* __restrict__ wht,
    int* __restrict__ counts)
{
    if (blockIdx.x == 0 && threadIdx.x < NE) counts[threadIdx.x] = 0;
    __shared__ float tile[32][33];
    const int t = threadIdx.x;
    int bid = blockIdx.x;
    const float* src; ushort_t* dst; int R, C, e, rt, ct;
    if (bid < NE * 96) {                       // W1: [384][256], 12x8 tiles
        e = bid / 96; int rem = bid % 96; rt = rem / 8; ct = rem % 8;
        src = W1; dst = w1t; R = D; C = H1;
    } else {                                   // Wh: [256][192], 8x6 tiles
        bid -= NE * 96;
        e = bid / 48; int rem = bid % 48; rt = rem / 6; ct = rem % 6;
        src = Wh; dst = wht; R = H1; C = H2;
    }
    const float* S  = src + ((size_t)e * R + rt * 32) * C + ct * 32;
    ushort_t*    Dp = dst + ((size_t)e * C + ct * 32) * R + rt * 32;
    {
        int row = t >> 3, c4 = (t & 7) * 4;
        float4 v = *(const float4*)(S + (size_t)row * C + c4);
        tile[row][c4 + 0] = v.x; tile[row][c4 + 1] = v.y;
        tile[row][c4 + 2] = v.z; tile[row][c4 + 3] = v.w;
    }
    __syncthreads();
    {
        int orow = t >> 3, k4 = (t & 7) * 4;
        ushort4 o;
        o.x = f2bf(tile[k4 + 0][orow]);
        o.y = f2bf(tile[k4 + 1][orow]);
        o.z = f2bf(tile[k4 + 2][orow]);
        o.w = f2bf(tile[k4 + 3][orow]);
        *(ushort4*)(Dp + (size_t)orow * R + k4) = o;
    }
}

// 512 thr / 8 waves; TA=64; XOR-swizzled LDS; H1t aliases Xt;
// weights: inline-asm global loads, depth-4 ring, counted vmcnt (T4)
__global__ __launch_bounds__(512, 4) void mlp_kernel(
    const float*    __restrict__ rep,
    const int*      __restrict__ counts,
    const int*      __restrict__ bucket,
    const ushort_t* __restrict__ w1t,      // [E][H1][D]  bf16
    const ushort_t* __restrict__ wht,      // [E][H2][H1] bf16
    const float*    __restrict__ b1,
    const float*    __restrict__ bh,
    const float*    __restrict__ W2,
    const float*    __restrict__ b2,
    float*          __restrict__ energy)
{
    const int c0 = counts[0], c1 = counts[1], c2 = counts[2], c3 = counts[3];
    const int t0 = (c0 + 63) >> 6, t1 = (c1 + 63) >> 6, t2 = (c2 + 63) >> 6;
    const int t3 = (c3 + 63) >> 6;
    int bid = blockIdx.x;
    int e, tile, n;
    if      (bid < t0)                { e = 0; tile = bid;                n = c0; }
    else if (bid < t0 + t1)           { e = 1; tile = bid - t0;           n = c1; }
    else if (bid < t0 + t1 + t2)      { e = 2; tile = bid - t0 - t1;      n = c2; }
    else if (bid < t0 + t1 + t2 + t3) { e = 3; tile = bid - t0 - t1 - t2; n = c3; }
    else return;
    const int base = tile * TA;

    const int t    = threadIdx.x;
    const int lane = t & 63;
    const int wv   = t >> 6;        // 0..7
    const int g    = lane >> 4;
    const int r    = lane & 15;
    const int r7   = r & 7;

    __shared__ ushort_t smem[TA * D];          // 49,152 B
    ushort_t* Xt  = smem;                      // [64][384] swizzled
    ushort_t* H1t = smem;                      // [64][256] swizzled — ALIASES Xt
    float*    eparts = (float*)(smem + 20480); // bytes 40960.. (above H1t's 32768)

    const int koff1 = (bid & 3) * 3;           // per-block K-order stagger
    const int koff2 = (bid & 3) * 2;
    const ushort_t* a1p = w1t + ((size_t)e * H1 + wv * 32 + r) * D + g * 8;
    const ushort_t* a2p = wht + ((size_t)e * H2 + wv * 32 + r) * H1 + g * 8;

    // ---- stage X (64x384): batch-issue all 12 loads, then convert+store swizzled
    {
        const int srow = t >> 3, scs = t & 7, sswz = srow & 7;
        int ai = base + srow;
        int gs = bucket[(e << 15) + (ai < n ? ai : base)];
        const float* xp = rep + (size_t)gs * D;
        float4 xv[12];
        #pragma unroll
        for (int i = 0; i < 6; ++i) {
            const int cs = scs + 8 * i;
            xv[2 * i]     = *(const float4*)(xp + cs * 8);
            xv[2 * i + 1] = *(const float4*)(xp + cs * 8 + 4);
        }
        __builtin_amdgcn_sched_barrier(0);     // pin issue order: loads stay batched
        #pragma unroll
        for (int i = 0; i < 6; ++i) {
            const int cs = scs + 8 * i;
            union { bf16x8 v; ushort_t u[8]; } pk;
            pk.u[0] = f2bf(xv[2*i].x);   pk.u[1] = f2bf(xv[2*i].y);
            pk.u[2] = f2bf(xv[2*i].z);   pk.u[3] = f2bf(xv[2*i].w);
            pk.u[4] = f2bf(xv[2*i+1].x); pk.u[5] = f2bf(xv[2*i+1].y);
            pk.u[6] = f2bf(xv[2*i+1].z); pk.u[7] = f2bf(xv[2*i+1].w);
            *(bf16x8*)(Xt + srow * D + ((cs ^ sswz) << 3)) = pk.v;
        }
    }

    // ---- phase-1 ring prologue BEFORE barrier: barrier's vmcnt(0) drain = free
    uint4 af[4][2];
    #pragma unroll
    for (int p = 0; p < 4; ++p) {
        int kse = p + koff1; if (kse >= 12) kse -= 12;
        af[p][0] = gload16(a1p + kse * 32);
        af[p][1] = gload16(a1p + 16 * D + kse * 32);
    }
    __syncthreads();

    // ---- phase 1: C1^T; unrolled; counted-vmcnt ring
    f32x4 acc1[2][4];
    #pragma unroll
    for (int nn = 0; nn < 2; ++nn)
        #pragma unroll
        for (int m = 0; m < 4; ++m)
            acc1[nn][m] = (f32x4){0.f, 0.f, 0.f, 0.f};

    #pragma unroll
    for (int ks = 0; ks < 12; ++ks) {
        if (ks <= 8) { WAITV6; } else if (ks == 9) { WAITV4; }
        else if (ks == 10) { WAITV2; } else { WAITV0; }
        const int s = ks & 3;
        uint4 aw0 = af[s][0], aw1 = af[s][1];      // pair ks (now complete)
        if (ks + 4 < 12) {                          // refill slot with pair ks+4
            int ksn = ks + 4 + koff1; if (ksn >= 12) ksn -= 12;
            af[s][0] = gload16(a1p + ksn * 32);
            af[s][1] = gload16(a1p + 16 * D + ksn * 32);
        }
        int kse = ks + koff1; if (kse >= 12) kse -= 12;
        bf16x8 bx[4];
        #pragma unroll
        for (int m = 0; m < 4; ++m) {
            const int cs = kse * 4 + g;
            bx[m] = *(const bf16x8*)(Xt + (m * 16 + r) * D + ((cs ^ r7) << 3));
        }
        #pragma unroll
        for (int m = 0; m < 4; ++m) {
            acc1[0][m] = __builtin_amdgcn_mfma_f32_16x16x32_bf16(
                __builtin_bit_cast(bf16x8, aw0), bx[m], acc1[0][m], 0, 0, 0);
            acc1[1][m] = __builtin_amdgcn_mfma_f32_16x16x32_bf16(
                __builtin_bit_cast(bf16x8, aw1), bx[m], acc1[1][m], 0, 0, 0);
        }
    }
    __syncthreads();   // all waves done READING Xt; safe to overwrite with H1t

    // ---- phase-2 ring prologue (drained free by the next barrier)
    uint4 af2[4][2];
    if (wv < 6) {
        #pragma unroll
        for (int p = 0; p < 4; ++p) {
            int kse = p + koff2; if (kse >= 8) kse -= 8;
            af2[p][0] = gload16(a2p + kse * 32);
            af2[p][1] = gload16(a2p + 16 * H1 + kse * 32);
        }
    }

    // ---- +b1, pack, write H1t (swizzled, aliases Xt)
    #pragma unroll
    for (int nn = 0; nn < 2; ++nn) {
        float bv[4];
        #pragma unroll
        for (int q = 0; q < 4; ++q)
            bv[q] = b1[e * H1 + wv * 32 + nn * 16 + g * 4 + q];
        #pragma unroll
        for (int m = 0; m < 4; ++m) {
            unsigned p0 = f2bf(acc1[nn][m][0] + bv[0]);
            unsigned p1 = f2bf(acc1[nn][m][1] + bv[1]);
            unsigned p2 = f2bf(acc1[nn][m][2] + bv[2]);
            unsigned p3 = f2bf(acc1[nn][m][3] + bv[3]);
            uint2 pk; pk.x = p0 | (p1 << 16); pk.y = p2 | (p3 << 16);
            const int col = wv * 32 + nn * 16 + g * 4;
            const int cs  = col >> 3;
            const int phys = (m * 16 + r) * H1 + ((cs ^ r7) << 3) + (col & 7);
            *(uint2*)(H1t + phys) = pk;
        }
    }
    __syncthreads();

    // ---- phase 2: C2^T; waves 0..5; unrolled; counted-vmcnt ring
    f32x4 acc2[2][4];
    #pragma unroll
    for (int nn = 0; nn < 2; ++nn)
        #pragma unroll
        for (int m = 0; m < 4; ++m)
            acc2[nn][m] = (f32x4){0.f, 0.f, 0.f, 0.f};

    if (wv < 6) {
        #pragma unroll
        for (int ks = 0; ks < 8; ++ks) {
            if (ks <= 4) { WAITV6; } else if (ks == 5) { WAITV4; }
            else if (ks == 6) { WAITV2; } else { WAITV0; }
            const int s = ks & 3;
            uint4 aw0 = af2[s][0], aw1 = af2[s][1];
            if (ks + 4 < 8) {
                int ksn = ks + 4 + koff2; if (ksn >= 8) ksn -= 8;
                af2[s][0] = gload16(a2p + ksn * 32);
                af2[s][1] = gload16(a2p + 16 * H1 + ksn * 32);
            }
            int kse = ks + koff2; if (kse >= 8) kse -= 8;
            bf16x8 bx[4];
            #pragma unroll
            for (int m = 0; m < 4; ++m) {
                const int cs = kse * 4 + g;
                bx[m] = *(const bf16x8*)(H1t + (m * 16 + r) * H1 + ((cs ^ r7) << 3));
            }
            #pragma unroll
            for (int m = 0; m < 4; ++m) {
                acc2[0][m] = __builtin_amdgcn_mfma_f32_16x16x32_bf16(
                    __builtin_bit_cast(bf16x8, aw0), bx[m], acc2[0][m], 0, 0, 0);
                acc2[1][m] = __builtin_amdgcn_mfma_f32_16x16x32_bf16(
                    __builtin_bit_cast(bf16x8, aw1), bx[m], acc2[1][m], 0, 0, 0);
            }
        }

        // epilogue part 1: relu(C2^T+bh)·W2, reduce this wave's 32 cols
        #pragma unroll
        for (int m = 0; m < 4; ++m) {
            float s = 0.f;
            #pragma unroll
            for (int nn = 0; nn < 2; ++nn) {
                float bhv[4], w2v[4];
                #pragma unroll
                for (int q = 0; q < 4; ++q) {
                    int h2i = e * H2 + wv * 32 + nn * 16 + g * 4 + q;
                    bhv[q] = bh[h2i];
                    w2v[q] = W2[h2i];
                }
                #pragma unroll
                for (int q = 0; q < 4; ++q) {
                    float z = acc2[nn][m][q] + bhv[q];
                    z = fmaxf(z, 0.f);
                    s += z * w2v[q];
                }
            }
            s += __shfl_xor(s, 16, 64);
            s += __shfl_xor(s, 32, 64);
            if (lane < 16) eparts[wv * TA + m * 16 + r] = s;
        }
    }
    __syncthreads();

    // epilogue part 2: combine 6 wave-partials, add b2, store per-atom energy
    if (t < TA) {
        int ai = base + t;
        if (ai < n) {
            int gi = bucket[(e << 15) + ai];
            float tot = b2[e];
            #pragma unroll
            for (int w = 0; w < 6; ++w) tot += eparts[w * TA + t];
            energy[gi] = tot;
        }
    }
}

__global__ void reduce_kernel(const float* __restrict__ energy, float* __restrict__ out) {
    const int b = blockIdx.x, t = threadIdx.x;
    float s = 0.f;
    for (int i = t; i < NA; i += 256) s += energy[b * NA + i];
    for (int off = 32; off > 0; off >>= 1) s += __shfl_down(s, off, 64);
    __shared__ float ws[4];
    if ((t & 63) == 0) ws[t >> 6] = s;
    __syncthreads();
    if (t == 0) out[b] = ws[0] + ws[1] + ws[2] + ws[3];
}

extern "C" void kernel_launch(void* const* d_in, const int* in_sizes, int n_in,
                              void* d_out, int out_size, void* d_ws, size_t ws_size,
                              hipStream_t stream) {
    const float* rep     = (const float*)d_in[0];
    const int*   species = (const int*)  d_in[1];
    const float* W1      = (const float*)d_in[2];
    const float* b1      = (const float*)d_in[3];
    const float* Wh      = (const float*)d_in[4];
    const float* bh      = (const float*)d_in[5];
    const float* W2      = (const float*)d_in[6];
    const float* b2      = (const float*)d_in[7];
    float* out = (float*)d_out;

    char* ws = (char*)d_ws;
    int*      counts  = (int*)      (ws + 0);
    int*      bucket  = (int*)      (ws + 64);          // 512 KB
    float*    energy  = (float*)    (ws + 524352);      // 128 KB
    ushort_t* w1t     = (ushort_t*) (ws + 655424);      // 768 KB (16B-aligned)
    ushort_t* wht     = (ushort_t*) (ws + 1441856);     // 384 KB (16B-aligned)

    transpose_kernel<<<NE * 96 + NE * 48, 256, 0, stream>>>(W1, Wh, w1t, wht, counts);
    scatter_kernel<<<NATOMS / 256, 256, 0, stream>>>(species, counts, bucket);
    mlp_kernel<<<NGRID, 512, 0, stream>>>(rep, counts, bucket, w1t, wht,
                                          b1, bh, W2, b2, energy);
    reduce_kernel<<<NB, 256, 0, stream>>>(energy, out);
}